// Round 2
// baseline (884.355 us; speedup 1.0000x reference)
//
#include <hip/hip_runtime.h>
#include <math.h>

// Problem constants
#define NB 4096          // batch B
#define CC 128           // channels (GEMM K)
#define TT 10
#define JJ 22
#define MM 220           // sites per b = T*J (14 m-tiles of 16, padded)
#define WSTRIDE 68       // uint32 words per Wb row (136 bf16 = 128 + 8 pad)
#define OUT0_N 19824640  // 4096*10*22*22
#define OUT1_N 9011200   // 4096*22*10*10
#define BPB 8            // batches per GEMM block (grid 512 = 2 blocks/CU)

typedef __attribute__((ext_vector_type(8))) short bf16x8;
typedef __attribute__((ext_vector_type(4))) float f32x4;

// fp32 -> bf16 bits, round-to-nearest-even
__device__ __forceinline__ unsigned f2bf(float f) {
  union { float f; unsigned u; } v; v.f = f;
  return (v.u + 0x7FFFu + ((v.u >> 16) & 1u)) >> 16;
}

// MFMA A-fragment loads for one b: A[m = lane&15][k = quad*8 + j]
// src[b,c,m]: m contiguous -> lanes 0..15 coalesce; mtp pair covers 128B lines.
__device__ __forceinline__ void load_A(bf16x8 A[2][4], const float* __restrict__ srcb,
                                       int w, int l15, int quad) {
  #pragma unroll
  for (int mtp = 0; mtp < 2; ++mtp) {
    int m = w * 32 + mtp * 16 + l15;
    if (m > MM - 1) m = MM - 1;  // rows >=220 are dead (never stored)
    #pragma unroll
    for (int kf = 0; kf < 4; ++kf) {
      const float* p = srcb + (kf * 32 + quad * 8) * MM + m;
      bf16x8 f;
      #pragma unroll
      for (int j = 0; j < 8; ++j)
        f[j] = (short)f2bf(p[j * MM]);
      A[mtp][kf] = f;
    }
  }
}

// Key math fact: softmax_j(s_i + d_j) == softmax_j(d_j) (s_i cancels), so
// a_src_* is dead; we only need d_s, d_t per site -> GEMM-reduce kernel.
__global__ __launch_bounds__(448) void dms_gemm(
    const float* __restrict__ src,
    const float* __restrict__ Ws,
    const float* __restrict__ a_dst_s,
    const float* __restrict__ Wt,
    const float* __restrict__ a_dst_t,
    float* __restrict__ dws)   // d_s[4096*220] ++ d_t[4096*220]
{
  __shared__ unsigned lds_w[256 * WSTRIDE];  // Wb bf16 [256][136] = 69632 B
  __shared__ float a_l[256];                 // a_dst_s ++ a_dst_t

  const int tid  = threadIdx.x;
  const int w    = tid >> 6;     // wave 0..6 -> m-tiles 2w, 2w+1
  const int lane = tid & 63;
  const int l15  = lane & 15;
  const int quad = lane >> 4;

  // ---- stage Wb = [W_s ; W_t] as bf16, ONCE per block (amortized 8 b's) ----
  for (int p4 = tid; p4 < 256 * 64; p4 += 448) {
    int n = p4 >> 6, kw = p4 & 63;
    const float* wp = (n < 128) ? (Ws + n * CC + kw * 2)
                                : (Wt + (n - 128) * CC + kw * 2);
    lds_w[n * WSTRIDE + kw] = f2bf(wp[0]) | (f2bf(wp[1]) << 16);
  }
  if (tid < 256)
    a_l[tid] = (tid < 128) ? a_dst_s[tid] : a_dst_t[tid - 128];
  __syncthreads();
  // no further barriers: all cross-lane traffic below is intra-wave

  const unsigned short* wl = (const unsigned short*)lds_w;
  const int b0 = blockIdx.x * BPB;

  bf16x8 Acur[2][4];
  load_A(Acur, src + (size_t)b0 * (CC * MM), w, l15, quad);

  for (int ib = 0; ib < BPB; ++ib) {
    const int b = b0 + ib;

    // prefetch next b's fragments during this b's MFMA work
    bf16x8 Anext[2][4];
    if (ib < BPB - 1)
      load_A(Anext, src + (size_t)(b + 1) * (CC * MM), w, l15, quad);

    // ---- GEMM: x = A @ Wb^T, fused lrelu + a-weighted reduce over n ----
    // C/D layout: col = lane&15 (n), row = quad*4 + r (m)
    f32x4 part_s0 = {0,0,0,0}, part_s1 = {0,0,0,0};
    f32x4 part_t0 = {0,0,0,0}, part_t1 = {0,0,0,0};
    #pragma unroll
    for (int nt = 0; nt < 16; ++nt) {
      const bf16x8* bp = (const bf16x8*)(wl + (nt * 16 + l15) * (WSTRIDE * 2) + quad * 8);
      f32x4 acc0 = {0,0,0,0}, acc1 = {0,0,0,0};
      #pragma unroll
      for (int kf = 0; kf < 4; ++kf) {
        bf16x8 bb = bp[kf * 4];
        acc0 = __builtin_amdgcn_mfma_f32_16x16x32_bf16(Acur[0][kf], bb, acc0, 0, 0, 0);
        acc1 = __builtin_amdgcn_mfma_f32_16x16x32_bf16(Acur[1][kf], bb, acc1, 0, 0, 0);
      }
      float av = a_l[nt * 16 + l15];
      #pragma unroll
      for (int r = 0; r < 4; ++r) {
        float x0 = fmaxf(acc0[r], 0.2f * acc0[r]);  // lrelu(x) = max(x, 0.2x)
        float x1 = fmaxf(acc1[r], 0.2f * acc1[r]);
        if (nt < 8) { part_s0[r] += av * x0; part_s1[r] += av * x1; }
        else        { part_t0[r] += av * x0; part_t1[r] += av * x1; }
      }
    }

    // reduce across the 16 lanes sharing a row (low 4 lane bits)
    #pragma unroll
    for (int mk = 1; mk <= 8; mk <<= 1) {
      #pragma unroll
      for (int r = 0; r < 4; ++r) {
        part_s0[r] += __shfl_xor(part_s0[r], mk);
        part_s1[r] += __shfl_xor(part_s1[r], mk);
        part_t0[r] += __shfl_xor(part_t0[r], mk);
        part_t1[r] += __shfl_xor(part_t1[r], mk);
      }
    }
    if (l15 == 0) {
      float* dsb = dws + (size_t)b * MM;
      float* dtb = dws + (size_t)NB * MM + (size_t)b * MM;
      #pragma unroll
      for (int r = 0; r < 4; ++r) {
        int m0 = w * 32 + quad * 4 + r;
        if (m0 < MM) { dsb[m0] = part_s0[r]; dtb[m0] = part_t0[r]; }
        int m1 = w * 32 + 16 + quad * 4 + r;
        if (m1 < MM) { dsb[m1] = part_s1[r]; dtb[m1] = part_t1[r]; }
      }
    }

    if (ib < BPB - 1) {
      #pragma unroll
      for (int mtp = 0; mtp < 2; ++mtp)
        #pragma unroll
        for (int kf = 0; kf < 4; ++kf)
          Acur[mtp][kf] = Anext[mtp][kf];
    }
  }
}

// Softmax + broadcast + bias. Tiny LDS -> high occupancy; float4 stores.
__global__ __launch_bounds__(256) void dms_epilogue(
    const float* __restrict__ dws,
    const float* __restrict__ sa_bias,
    const float* __restrict__ ta_bias,
    float* __restrict__ out)
{
  __shared__ __align__(16) float ds_l[MM];
  __shared__ __align__(16) float dt_l[MM];
  __shared__ __align__(16) float sab_l[484];
  __shared__ __align__(16) float tab_l[100];

  const int tid  = threadIdx.x;
  const int w    = tid >> 6;   // wave 0..3
  const int lane = tid & 63;
  const int b    = blockIdx.x;

  const float* dsp = dws + (size_t)b * MM;
  const float* dtp = dws + (size_t)NB * MM + (size_t)b * MM;
  for (int i = tid; i < MM; i += 256) { ds_l[i] = dsp[i]; dt_l[i] = dtp[i]; }
  for (int i = tid; i < 484; i += 256) sab_l[i] = sa_bias[i];
  if (tid < 100) tab_l[tid] = ta_bias[tid];
  __syncthreads();

  // ---- spatial: out0[b,t,i,j] = softmax_j(d_s[t,:])[j] + sab[i,j] ----
  for (int t = w; t < TT; t += 4) {
    float e = (lane < JJ) ? ds_l[t * JJ + lane] : -1e30f;
    float mx = e;
    #pragma unroll
    for (int mk = 1; mk < 64; mk <<= 1) mx = fmaxf(mx, __shfl_xor(mx, mk));
    float pp = (lane < JJ) ? __expf(e - mx) : 0.f;
    float ss = pp;
    #pragma unroll
    for (int mk = 1; mk < 64; mk <<= 1) ss += __shfl_xor(ss, mk);
    pp = pp / ss;
    float4* o = (float4*)(out + (size_t)(b * TT + t) * 484);  // 484 = 121*4
    const float4* bias4 = (const float4*)sab_l;
    for (int f = lane; f < 121; f += 64) {
      float4 bv = bias4[f];
      float4 v;
      v.x = __shfl(pp, (4 * f + 0) % JJ) + bv.x;
      v.y = __shfl(pp, (4 * f + 1) % JJ) + bv.y;
      v.z = __shfl(pp, (4 * f + 2) % JJ) + bv.z;
      v.w = __shfl(pp, (4 * f + 3) % JJ) + bv.w;
      o[f] = v;
    }
  }

  // ---- temporal: out1[b,j,i,t] = softmax_t(d_t[:,j])[t] + tab[i,t] ----
  float* out1 = out + (size_t)OUT0_N;
  for (int j = w; j < JJ; j += 4) {
    float e = (lane < TT) ? dt_l[lane * JJ + j] : -1e30f;
    float mx = e;
    #pragma unroll
    for (int mk = 1; mk < 64; mk <<= 1) mx = fmaxf(mx, __shfl_xor(mx, mk));
    float qq = (lane < TT) ? __expf(e - mx) : 0.f;
    float ss = qq;
    #pragma unroll
    for (int mk = 1; mk < 64; mk <<= 1) ss += __shfl_xor(ss, mk);
    qq = qq / ss;
    float4* o = (float4*)(out1 + (size_t)(b * JJ + j) * 100);  // 100 = 25*4
    const float4* bias4 = (const float4*)tab_l;
    float4 v;
    float4 bv = (lane < 25) ? bias4[lane] : make_float4(0, 0, 0, 0);
    v.x = __shfl(qq, (4 * lane + 0) % TT) + bv.x;
    v.y = __shfl(qq, (4 * lane + 1) % TT) + bv.y;
    v.z = __shfl(qq, (4 * lane + 2) % TT) + bv.z;
    v.w = __shfl(qq, (4 * lane + 3) % TT) + bv.w;
    if (lane < 25) o[lane] = v;
  }

  // 4 trailing scalar zeros of the output tuple
  if (b == 0 && tid < 4) out[(size_t)OUT0_N + OUT1_N + tid] = 0.f;
}

extern "C" void kernel_launch(void* const* d_in, const int* in_sizes, int n_in,
                              void* d_out, int out_size, void* d_ws, size_t ws_size,
                              hipStream_t stream) {
  const float* src = (const float*)d_in[0];
  const float* Ws  = (const float*)d_in[1];
  // d_in[2] = a_src_s, d_in[5] = a_src_t: mathematically dead (softmax cancel)
  const float* ads = (const float*)d_in[3];
  const float* Wt  = (const float*)d_in[4];
  const float* adt = (const float*)d_in[6];
  const float* sab = (const float*)d_in[7];
  const float* tab = (const float*)d_in[8];
  float* dws = (float*)d_ws;  // 2 * 4096 * 220 floats = 7.2 MB

  dms_gemm<<<NB / BPB, 448, 0, stream>>>(src, Ws, ads, Wt, adt, dws);
  dms_epilogue<<<NB, 256, 0, stream>>>(dws, sab, tab, (float*)d_out);
}